// Round 1
// baseline (1933.067 us; speedup 1.0000x reference)
//
#include <hip/hip_runtime.h>
#include <cstdint>
#include <cstddef>
#include <cmath>

// Problem constants (fixed by the reference)
#define N0C 600000
#define N1C 100000
#define N2C 10000
#define N3C 1000
#define E0C 1000000
#define E1C 100000
#define E2C 10000
#define DINC 128
#define DHC 256
#define DOUTC 47

// -------------------- scatter-mean (atomic) --------------------
// dim=128: one wave per edge, each lane handles 2 floats (float2 load).
__global__ __launch_bounds__(256) void scatter128(
    const float* __restrict__ X, const int* __restrict__ src,
    const int* __restrict__ dst, int E,
    float* __restrict__ agg, float* __restrict__ cnt) {
  int lane = threadIdx.x & 63;
  int wave = (blockIdx.x * blockDim.x + threadIdx.x) >> 6;
  int nw = (gridDim.x * blockDim.x) >> 6;
  for (int e = wave; e < E; e += nw) {
    int s = src[e];
    int d = dst[e];
    float2 v = *(const float2*)(X + (size_t)s * 128 + lane * 2);
    float* base = agg + (size_t)d * 128 + lane * 2;
    atomicAdd(base, v.x);
    atomicAdd(base + 1, v.y);
    if (lane == 0) atomicAdd(cnt + d, 1.0f);
  }
}

// dim=256: one wave per edge, each lane handles 4 floats (float4 load).
__global__ __launch_bounds__(256) void scatter256(
    const float* __restrict__ X, const int* __restrict__ src,
    const int* __restrict__ dst, int E,
    float* __restrict__ agg, float* __restrict__ cnt) {
  int lane = threadIdx.x & 63;
  int wave = (blockIdx.x * blockDim.x + threadIdx.x) >> 6;
  int nw = (gridDim.x * blockDim.x) >> 6;
  for (int e = wave; e < E; e += nw) {
    int s = src[e];
    int d = dst[e];
    float4 v = *(const float4*)(X + (size_t)s * 256 + lane * 4);
    float* base = agg + (size_t)d * 256 + lane * 4;
    atomicAdd(base + 0, v.x);
    atomicAdd(base + 1, v.y);
    atomicAdd(base + 2, v.z);
    atomicAdd(base + 3, v.w);
    if (lane == 0) atomicAdd(cnt + d, 1.0f);
  }
}

__global__ void invcnt_kernel(const float* __restrict__ cnt,
                              float* __restrict__ invc, int n) {
  int i = blockIdx.x * blockDim.x + threadIdx.x;
  if (i < n) invc[i] = 1.0f / fmaxf(cnt[i], 1.0f);
}

// -------------------- fused concat-K GEMM --------------------
// C[M, 256] = relu?( [A1*invc | A2] @ [B1 ; B2] + bias )
// A1: [M, K1] row-major (agg, scaled per-row by invc), A2: [M, K2] (x_tgt).
// B1: [K1, ldb], B2: [K2, ldb] row-major.  Tile: 128x128, BK=8, 8x8/thread.
__global__ __launch_bounds__(256) void gemm_cat(
    const float* __restrict__ A1, int lda1, int K1, const float* __restrict__ invc,
    const float* __restrict__ A2, int lda2, int K2,
    const float* __restrict__ B1, const float* __restrict__ B2, int ldb,
    const float* __restrict__ bias, float* __restrict__ C, int ldc,
    int M, int do_relu) {
  __shared__ float As[8][128];
  __shared__ float Bs[8][128];
  const int tid = threadIdx.x;
  const int rowBase = blockIdx.x * 128;
  const int colBase = blockIdx.y * 128;
  const int am = tid >> 1;            // A-load row within tile (0..127)
  const int ak = (tid & 1) * 4;       // A-load k offset (0 or 4)
  const int bk = tid >> 5;            // B-load k row (0..7)
  const int bn = (tid & 31) * 4;      // B-load col (0..124)
  const int ty = tid >> 4;            // 0..15 -> 8 rows each
  const int tx = tid & 15;            // 0..15 -> 8 cols each
  const int K = K1 + K2;

  float acc[8][8];
#pragma unroll
  for (int i = 0; i < 8; i++)
#pragma unroll
    for (int j = 0; j < 8; j++) acc[i][j] = 0.0f;

  const int arow = rowBase + am;
  const int rclamp = arow < M ? arow : (M - 1);

  for (int kt = 0; kt < K; kt += 8) {
    // stage A (select source by k; K1 % 8 == 0 so a float4 never straddles)
    int kk = kt + ak;
    float4 av;
    if (kk < K1) {
      av = *(const float4*)(A1 + (size_t)rclamp * lda1 + kk);
      float s = invc[rclamp];
      av.x *= s; av.y *= s; av.z *= s; av.w *= s;
    } else {
      av = *(const float4*)(A2 + (size_t)rclamp * lda2 + (kk - K1));
    }
    // stage B
    int kb = kt + bk;
    float4 bv;
    if (kb < K1) bv = *(const float4*)(B1 + (size_t)kb * ldb + colBase + bn);
    else         bv = *(const float4*)(B2 + (size_t)(kb - K1) * ldb + colBase + bn);

    __syncthreads();  // previous tile's LDS reads done
    As[ak + 0][am] = av.x;
    As[ak + 1][am] = av.y;
    As[ak + 2][am] = av.z;
    As[ak + 3][am] = av.w;
    *(float4*)&Bs[bk][bn] = bv;
    __syncthreads();

#pragma unroll
    for (int k = 0; k < 8; k++) {
      float a[8], b[8];
      *(float4*)&a[0] = *(const float4*)&As[k][ty * 8];
      *(float4*)&a[4] = *(const float4*)&As[k][ty * 8 + 4];
      *(float4*)&b[0] = *(const float4*)&Bs[k][tx * 8];
      *(float4*)&b[4] = *(const float4*)&Bs[k][tx * 8 + 4];
#pragma unroll
      for (int i = 0; i < 8; i++)
#pragma unroll
        for (int j = 0; j < 8; j++) acc[i][j] += a[i] * b[j];
    }
  }

  // epilogue: bias + relu, float4 stores
#pragma unroll
  for (int i = 0; i < 8; i++) {
    int row = rowBase + ty * 8 + i;
    if (row < M) {
      float4 o0, o1;
      const int cb = colBase + tx * 8;
      o0.x = acc[i][0] + bias[cb + 0];
      o0.y = acc[i][1] + bias[cb + 1];
      o0.z = acc[i][2] + bias[cb + 2];
      o0.w = acc[i][3] + bias[cb + 3];
      o1.x = acc[i][4] + bias[cb + 4];
      o1.y = acc[i][5] + bias[cb + 5];
      o1.z = acc[i][6] + bias[cb + 6];
      o1.w = acc[i][7] + bias[cb + 7];
      if (do_relu) {
        o0.x = fmaxf(o0.x, 0.f); o0.y = fmaxf(o0.y, 0.f);
        o0.z = fmaxf(o0.z, 0.f); o0.w = fmaxf(o0.w, 0.f);
        o1.x = fmaxf(o1.x, 0.f); o1.y = fmaxf(o1.y, 0.f);
        o1.z = fmaxf(o1.z, 0.f); o1.w = fmaxf(o1.w, 0.f);
      }
      *(float4*)(C + (size_t)row * ldc + cb) = o0;
      *(float4*)(C + (size_t)row * ldc + cb + 4) = o1;
    }
  }
}

// -------------------- layer 2 + log_softmax --------------------
// One 64-thread block per output row. out[i][j] = logsoftmax(mean2@Wl2 + b2 + h2@Wr2)
__global__ __launch_bounds__(64) void layer2_lsm(
    const float* __restrict__ agg2, const float* __restrict__ invc2,
    const float* __restrict__ h2, const float* __restrict__ Wl2,
    const float* __restrict__ Wr2, const float* __restrict__ b2,
    float* __restrict__ out) {
  __shared__ float arow[512];
  const int i = blockIdx.x;
  const int lane = threadIdx.x;
  const float inv = invc2[i];
  for (int t = lane; t < 256; t += 64) {
    arow[t] = agg2[(size_t)i * 256 + t] * inv;
    arow[256 + t] = h2[(size_t)i * 256 + t];
  }
  __syncthreads();
  float acc = 0.0f;
  if (lane < 47) {
    acc = b2[lane];
#pragma unroll 4
    for (int k = 0; k < 256; k++) acc += arow[k] * Wl2[k * 47 + lane];
#pragma unroll 4
    for (int k = 0; k < 256; k++) acc += arow[256 + k] * Wr2[k * 47 + lane];
  }
  float v = (lane < 47) ? acc : -INFINITY;
#pragma unroll
  for (int off = 32; off >= 1; off >>= 1) v = fmaxf(v, __shfl_xor(v, off, 64));
  float e = (lane < 47) ? expf(acc - v) : 0.0f;
  float s = e;
#pragma unroll
  for (int off = 32; off >= 1; off >>= 1) s += __shfl_xor(s, off, 64);
  if (lane < 47) out[(size_t)i * 47 + lane] = acc - v - logf(s);
}

// -------------------- launch --------------------
extern "C" void kernel_launch(void* const* d_in, const int* in_sizes, int n_in,
                              void* d_out, int out_size, void* d_ws, size_t ws_size,
                              hipStream_t stream) {
  (void)in_sizes; (void)n_in; (void)out_size; (void)ws_size;
  const float* x   = (const float*)d_in[0];
  const int* src0  = (const int*)d_in[1];
  const int* dst0  = (const int*)d_in[2];
  const int* src1  = (const int*)d_in[3];
  const int* dst1  = (const int*)d_in[4];
  const int* src2  = (const int*)d_in[5];
  const int* dst2  = (const int*)d_in[6];
  const float* Wl0 = (const float*)d_in[7];
  const float* Wr0 = (const float*)d_in[8];
  const float* b0  = (const float*)d_in[9];
  const float* Wl1 = (const float*)d_in[10];
  const float* Wr1 = (const float*)d_in[11];
  const float* b1  = (const float*)d_in[12];
  const float* Wl2 = (const float*)d_in[13];
  const float* Wr2 = (const float*)d_in[14];
  const float* b2  = (const float*)d_in[15];

  // workspace layout (floats); layer>=1 buffers overlay agg0's region
  float* ws = (float*)d_ws;
  float* agg0  = ws;                       // 12,800,000 (N1*128)
  float* cnt0  = ws + 12800000;            // 100,000
  float* invc0 = cnt0 + 100000;            // 100,000
  float* h1    = invc0 + 100000;           // 25,600,000 (N1*256)  [peak: 154.4 MB]
  float* agg1  = agg0;                     // 2,560,000 (N2*256) overlays dead agg0
  float* cnt1  = agg1 + 2560000;           // 10,000
  float* invc1 = cnt1 + 10000;             // 10,000
  float* h2    = invc1 + 10000;            // 2,560,000 (N2*256)
  float* agg2  = h2 + 2560000;             // 256,000 (N3*256)
  float* cnt2  = agg2 + 256000;            // 1,000
  float* invc2 = cnt2 + 1000;              // 1,000
  float* out   = (float*)d_out;

  // ---- layer 0 ----
  hipMemsetAsync(agg0, 0, (size_t)(12800000 + 100000) * 4, stream);  // agg0+cnt0
  scatter128<<<2048, 256, 0, stream>>>(x, src0, dst0, E0C, agg0, cnt0);
  invcnt_kernel<<<(N1C + 255) / 256, 256, 0, stream>>>(cnt0, invc0, N1C);
  gemm_cat<<<dim3(782, 2), 256, 0, stream>>>(
      agg0, 128, 128, invc0, x, 128, 128, Wl0, Wr0, 256, b0, h1, 256, N1C, 1);

  // ---- layer 1 ----
  hipMemsetAsync(agg1, 0, (size_t)(2560000 + 10000) * 4, stream);    // agg1+cnt1
  scatter256<<<512, 256, 0, stream>>>(h1, src1, dst1, E1C, agg1, cnt1);
  invcnt_kernel<<<(N2C + 255) / 256, 256, 0, stream>>>(cnt1, invc1, N2C);
  gemm_cat<<<dim3(79, 2), 256, 0, stream>>>(
      agg1, 256, 256, invc1, h1, 256, 256, Wl1, Wr1, 256, b1, h2, 256, N2C, 1);

  // ---- layer 2 + log_softmax ----
  hipMemsetAsync(agg2, 0, (size_t)(256000 + 1000) * 4, stream);      // agg2+cnt2
  scatter256<<<64, 256, 0, stream>>>(h2, src2, dst2, E2C, agg2, cnt2);
  invcnt_kernel<<<(N3C + 255) / 256, 256, 0, stream>>>(cnt2, invc2, N3C);
  layer2_lsm<<<N3C, 64, 0, stream>>>(agg2, invc2, h2, Wl2, Wr2, b2, out);
}

// Round 2
// 972.343 us; speedup vs baseline: 1.9881x; 1.9881x over previous
//
#include <hip/hip_runtime.h>
#include <cstdint>
#include <cstddef>
#include <cmath>

// Problem constants (fixed by the reference)
#define N0C 600000
#define N1C 100000
#define N2C 10000
#define N3C 1000
#define E0C 1000000
#define E1C 100000
#define E2C 10000

// -------------------- CSR build: histogram --------------------
__global__ __launch_bounds__(256) void hist_kernel(
    const int* __restrict__ dst, int E, int* __restrict__ cnt) {
  int i = blockIdx.x * blockDim.x + threadIdx.x;
  if (i < E) atomicAdd(&cnt[dst[i]], 1);
}

// -------------------- CSR build: block-level inclusive scan --------------------
// Each block scans CHUNK=1024 elements (256 thr x 4), in-place (incl == cnt ok),
// writes block total to partials[b].
__global__ __launch_bounds__(256) void scan_block(
    int* __restrict__ data, int n, int* __restrict__ partials) {
  __shared__ int sdata[256];
  const int t = threadIdx.x;
  const int base = blockIdx.x * 1024;
  const int idx = base + t * 4;
  int v[4];
  int sum = 0;
#pragma unroll
  for (int k = 0; k < 4; k++) {
    int x = (idx + k < n) ? data[idx + k] : 0;
    v[k] = x; sum += x;
  }
  sdata[t] = sum;
  __syncthreads();
  for (int off = 1; off < 256; off <<= 1) {
    int x = (t >= off) ? sdata[t - off] : 0;
    __syncthreads();
    sdata[t] += x;
    __syncthreads();
  }
  int run = (t > 0) ? sdata[t - 1] : 0;
#pragma unroll
  for (int k = 0; k < 4; k++) {
    run += v[k];
    if (idx + k < n) data[idx + k] = run;  // inclusive scan, in place
  }
  if (t == 255) partials[blockIdx.x] = sdata[255];
}

// exclusive scan of partials in place (nb <= 1024), one block of 1024 threads
__global__ __launch_bounds__(1024) void scan_partials(int* __restrict__ partials, int nb) {
  __shared__ int sdata[1024];
  const int t = threadIdx.x;
  sdata[t] = (t < nb) ? partials[t] : 0;
  __syncthreads();
  for (int off = 1; off < 1024; off <<= 1) {
    int x = (t >= off) ? sdata[t - off] : 0;
    __syncthreads();
    sdata[t] += x;
    __syncthreads();
  }
  int ex = (t > 0) ? sdata[t - 1] : 0;
  if (t < nb) partials[t] = ex;
}

// off[i+1] = incl[i] + partials[i>>10]; off[0] = 0
__global__ __launch_bounds__(256) void add_offsets(
    const int* __restrict__ incl, const int* __restrict__ partials, int n,
    int* __restrict__ off) {
  int i = blockIdx.x * blockDim.x + threadIdx.x;
  if (i < n) off[i + 1] = incl[i] + partials[i >> 10];
  if (i == 0) off[0] = 0;
}

// bucket fill: esrc[off[d] + cursor(d)++] = src[e]
__global__ __launch_bounds__(256) void fill_kernel(
    const int* __restrict__ src, const int* __restrict__ dst, int E,
    const int* __restrict__ off, int* __restrict__ cur, int* __restrict__ esrc) {
  int i = blockIdx.x * blockDim.x + threadIdx.x;
  if (i < E) {
    int d = dst[i];
    int p = atomicAdd(&cur[d], 1);
    esrc[off[d] + p] = src[i];
  }
}

// -------------------- CSR gather-mean --------------------
// dim=128: one wave per node; lane handles 2 floats.
__global__ __launch_bounds__(256) void gather128(
    const float* __restrict__ X, const int* __restrict__ off,
    const int* __restrict__ esrc, int Nt, float* __restrict__ mean) {
  int w = (blockIdx.x * blockDim.x + threadIdx.x) >> 6;
  int lane = threadIdx.x & 63;
  if (w >= Nt) return;
  int s = off[w], e = off[w + 1];
  float ax = 0.f, ay = 0.f;
  int j = s;
  for (; j + 1 < e; j += 2) {
    int s0 = esrc[j], s1 = esrc[j + 1];
    float2 v0 = *(const float2*)(X + (size_t)s0 * 128 + lane * 2);
    float2 v1 = *(const float2*)(X + (size_t)s1 * 128 + lane * 2);
    ax += v0.x + v1.x; ay += v0.y + v1.y;
  }
  if (j < e) {
    int s0 = esrc[j];
    float2 v0 = *(const float2*)(X + (size_t)s0 * 128 + lane * 2);
    ax += v0.x; ay += v0.y;
  }
  float inv = 1.0f / fmaxf((float)(e - s), 1.0f);
  float2 o; o.x = ax * inv; o.y = ay * inv;
  *(float2*)(mean + (size_t)w * 128 + lane * 2) = o;
}

// dim=256: one wave per node; lane handles 4 floats.
__global__ __launch_bounds__(256) void gather256(
    const float* __restrict__ X, const int* __restrict__ off,
    const int* __restrict__ esrc, int Nt, float* __restrict__ mean) {
  int w = (blockIdx.x * blockDim.x + threadIdx.x) >> 6;
  int lane = threadIdx.x & 63;
  if (w >= Nt) return;
  int s = off[w], e = off[w + 1];
  float ax = 0.f, ay = 0.f, az = 0.f, aw = 0.f;
  int j = s;
  for (; j + 1 < e; j += 2) {
    int s0 = esrc[j], s1 = esrc[j + 1];
    float4 v0 = *(const float4*)(X + (size_t)s0 * 256 + lane * 4);
    float4 v1 = *(const float4*)(X + (size_t)s1 * 256 + lane * 4);
    ax += v0.x + v1.x; ay += v0.y + v1.y; az += v0.z + v1.z; aw += v0.w + v1.w;
  }
  if (j < e) {
    int s0 = esrc[j];
    float4 v0 = *(const float4*)(X + (size_t)s0 * 256 + lane * 4);
    ax += v0.x; ay += v0.y; az += v0.z; aw += v0.w;
  }
  float inv = 1.0f / fmaxf((float)(e - s), 1.0f);
  float4 o; o.x = ax * inv; o.y = ay * inv; o.z = az * inv; o.w = aw * inv;
  *(float4*)(mean + (size_t)w * 256 + lane * 4) = o;
}

// -------------------- fused concat-K GEMM --------------------
// C[M, 256] = relu?( [A1 | A2] @ [B1 ; B2] + bias )
// A1: [M, K1] row-major (mean, pre-scaled), A2: [M, K2] (x_tgt).
// B1: [K1, ldb], B2: [K2, ldb] row-major.  Tile: 128x128, BK=8, 8x8/thread.
__global__ __launch_bounds__(256) void gemm_cat(
    const float* __restrict__ A1, int lda1, int K1,
    const float* __restrict__ A2, int lda2, int K2,
    const float* __restrict__ B1, const float* __restrict__ B2, int ldb,
    const float* __restrict__ bias, float* __restrict__ C, int ldc,
    int M, int do_relu) {
  __shared__ float As[8][128];
  __shared__ float Bs[8][128];
  const int tid = threadIdx.x;
  const int rowBase = blockIdx.x * 128;
  const int colBase = blockIdx.y * 128;
  const int am = tid >> 1;            // A-load row within tile (0..127)
  const int ak = (tid & 1) * 4;       // A-load k offset (0 or 4)
  const int bk = tid >> 5;            // B-load k row (0..7)
  const int bn = (tid & 31) * 4;      // B-load col (0..124)
  const int ty = tid >> 4;            // 0..15 -> 8 rows each
  const int tx = tid & 15;            // 0..15 -> 8 cols each
  const int K = K1 + K2;

  float acc[8][8];
#pragma unroll
  for (int i = 0; i < 8; i++)
#pragma unroll
    for (int j = 0; j < 8; j++) acc[i][j] = 0.0f;

  const int arow = rowBase + am;
  const int rclamp = arow < M ? arow : (M - 1);

  for (int kt = 0; kt < K; kt += 8) {
    int kk = kt + ak;
    float4 av;
    if (kk < K1) av = *(const float4*)(A1 + (size_t)rclamp * lda1 + kk);
    else         av = *(const float4*)(A2 + (size_t)rclamp * lda2 + (kk - K1));
    int kb = kt + bk;
    float4 bv;
    if (kb < K1) bv = *(const float4*)(B1 + (size_t)kb * ldb + colBase + bn);
    else         bv = *(const float4*)(B2 + (size_t)(kb - K1) * ldb + colBase + bn);

    __syncthreads();
    As[ak + 0][am] = av.x;
    As[ak + 1][am] = av.y;
    As[ak + 2][am] = av.z;
    As[ak + 3][am] = av.w;
    *(float4*)&Bs[bk][bn] = bv;
    __syncthreads();

#pragma unroll
    for (int k = 0; k < 8; k++) {
      float a[8], b[8];
      *(float4*)&a[0] = *(const float4*)&As[k][ty * 8];
      *(float4*)&a[4] = *(const float4*)&As[k][ty * 8 + 4];
      *(float4*)&b[0] = *(const float4*)&Bs[k][tx * 8];
      *(float4*)&b[4] = *(const float4*)&Bs[k][tx * 8 + 4];
#pragma unroll
      for (int i = 0; i < 8; i++)
#pragma unroll
        for (int j = 0; j < 8; j++) acc[i][j] += a[i] * b[j];
    }
  }

#pragma unroll
  for (int i = 0; i < 8; i++) {
    int row = rowBase + ty * 8 + i;
    if (row < M) {
      float4 o0, o1;
      const int cb = colBase + tx * 8;
      o0.x = acc[i][0] + bias[cb + 0];
      o0.y = acc[i][1] + bias[cb + 1];
      o0.z = acc[i][2] + bias[cb + 2];
      o0.w = acc[i][3] + bias[cb + 3];
      o1.x = acc[i][4] + bias[cb + 4];
      o1.y = acc[i][5] + bias[cb + 5];
      o1.z = acc[i][6] + bias[cb + 6];
      o1.w = acc[i][7] + bias[cb + 7];
      if (do_relu) {
        o0.x = fmaxf(o0.x, 0.f); o0.y = fmaxf(o0.y, 0.f);
        o0.z = fmaxf(o0.z, 0.f); o0.w = fmaxf(o0.w, 0.f);
        o1.x = fmaxf(o1.x, 0.f); o1.y = fmaxf(o1.y, 0.f);
        o1.z = fmaxf(o1.z, 0.f); o1.w = fmaxf(o1.w, 0.f);
      }
      *(float4*)(C + (size_t)row * ldc + cb) = o0;
      *(float4*)(C + (size_t)row * ldc + cb + 4) = o1;
    }
  }
}

// -------------------- layer 2 + log_softmax --------------------
__global__ __launch_bounds__(64) void layer2_lsm(
    const float* __restrict__ mean2, const float* __restrict__ h2,
    const float* __restrict__ Wl2, const float* __restrict__ Wr2,
    const float* __restrict__ b2, float* __restrict__ out) {
  __shared__ float arow[512];
  const int i = blockIdx.x;
  const int lane = threadIdx.x;
  for (int t = lane; t < 256; t += 64) {
    arow[t] = mean2[(size_t)i * 256 + t];
    arow[256 + t] = h2[(size_t)i * 256 + t];
  }
  __syncthreads();
  float acc = 0.0f;
  if (lane < 47) {
    acc = b2[lane];
#pragma unroll 4
    for (int k = 0; k < 256; k++) acc += arow[k] * Wl2[k * 47 + lane];
#pragma unroll 4
    for (int k = 0; k < 256; k++) acc += arow[256 + k] * Wr2[k * 47 + lane];
  }
  float v = (lane < 47) ? acc : -INFINITY;
#pragma unroll
  for (int off = 32; off >= 1; off >>= 1) v = fmaxf(v, __shfl_xor(v, off, 64));
  float e = (lane < 47) ? expf(acc - v) : 0.0f;
  float s = e;
#pragma unroll
  for (int off = 32; off >= 1; off >>= 1) s += __shfl_xor(s, off, 64);
  if (lane < 47) out[(size_t)i * 47 + lane] = acc - v - logf(s);
}

// -------------------- launch --------------------
extern "C" void kernel_launch(void* const* d_in, const int* in_sizes, int n_in,
                              void* d_out, int out_size, void* d_ws, size_t ws_size,
                              hipStream_t stream) {
  (void)in_sizes; (void)n_in; (void)out_size; (void)ws_size;
  const float* x   = (const float*)d_in[0];
  const int* src0  = (const int*)d_in[1];
  const int* dst0  = (const int*)d_in[2];
  const int* src1  = (const int*)d_in[3];
  const int* dst1  = (const int*)d_in[4];
  const int* src2  = (const int*)d_in[5];
  const int* dst2  = (const int*)d_in[6];
  const float* Wl0 = (const float*)d_in[7];
  const float* Wr0 = (const float*)d_in[8];
  const float* b0  = (const float*)d_in[9];
  const float* Wl1 = (const float*)d_in[10];
  const float* Wr1 = (const float*)d_in[11];
  const float* b1  = (const float*)d_in[12];
  const float* Wl2 = (const float*)d_in[13];
  const float* Wr2 = (const float*)d_in[14];
  const float* b2  = (const float*)d_in[15];

  // ---- workspace layout (overlays keep peak <= 153.6 MB + in-place ints) ----
  float* ws = (float*)d_ws;
  float* mean0 = ws;                         // 12,800,000 f  (N1*128)
  float* h1    = ws + 12800000;              // 25,600,000 f  (N1*256)
  // L0 int CSR buffers overlay h1's tail (dead before gemm0 writes h1):
  int* ib0   = (int*)(h1 + 25600000 - 1310720);
  int* cnt0  = ib0;                          // 100,000
  int* cur0  = cnt0 + 100000;                // 100,000
  int* off0  = cur0 + 100000;                // 100,001
  int* part0 = off0 + 100001;                // 128
  int* esrc0 = part0 + 128;                  // 1,000,000   (total 1,300,229 <= 1,310,720)
  // layer-1/2 buffers overlay dead mean0 (12.8M floats):
  float* mean1 = mean0;                      // 2,560,000 f (N2*256)
  float* h2    = mean1 + 2560000;            // 2,560,000 f
  float* mean2 = h2 + 2560000;               // 256,000 f  (N3*256)
  int* ib1   = (int*)(mean2 + 256000);
  int* cnt1  = ib1;                          // 10,000
  int* cur1  = cnt1 + 10000;                 // 10,000
  int* off1  = cur1 + 10000;                 // 10,001
  int* part1 = off1 + 10001;                 // 128
  int* esrc1 = part1 + 128;                  // 100,000
  int* ib2   = esrc1 + 100000;
  int* cnt2  = ib2;                          // 1,000
  int* cur2  = cnt2 + 1000;                  // 1,000
  int* off2  = cur2 + 1000;                  // 1,001
  int* part2 = off2 + 1001;                  // 128
  int* esrc2 = part2 + 128;                  // 10,000
  float* out = (float*)d_out;

  // ---- layer 0: CSR build + gather-mean + GEMM ----
  hipMemsetAsync(cnt0, 0, (size_t)200000 * 4, stream);  // cnt0 + cur0
  hist_kernel<<<(E0C + 255) / 256, 256, 0, stream>>>(dst0, E0C, cnt0);
  scan_block<<<(N1C + 1023) / 1024, 256, 0, stream>>>(cnt0, N1C, part0);
  scan_partials<<<1, 1024, 0, stream>>>(part0, (N1C + 1023) / 1024);
  add_offsets<<<(N1C + 255) / 256, 256, 0, stream>>>(cnt0, part0, N1C, off0);
  fill_kernel<<<(E0C + 255) / 256, 256, 0, stream>>>(src0, dst0, E0C, off0, cur0, esrc0);
  gather128<<<N1C / 4, 256, 0, stream>>>(x, off0, esrc0, N1C, mean0);
  gemm_cat<<<dim3(782, 2), 256, 0, stream>>>(
      mean0, 128, 128, x, 128, 128, Wl0, Wr0, 256, b0, h1, 256, N1C, 1);

  // ---- layer 1 ----
  hipMemsetAsync(cnt1, 0, (size_t)20000 * 4, stream);   // cnt1 + cur1
  hist_kernel<<<(E1C + 255) / 256, 256, 0, stream>>>(dst1, E1C, cnt1);
  scan_block<<<(N2C + 1023) / 1024, 256, 0, stream>>>(cnt1, N2C, part1);
  scan_partials<<<1, 1024, 0, stream>>>(part1, (N2C + 1023) / 1024);
  add_offsets<<<(N2C + 255) / 256, 256, 0, stream>>>(cnt1, part1, N2C, off1);
  fill_kernel<<<(E1C + 255) / 256, 256, 0, stream>>>(src1, dst1, E1C, off1, cur1, esrc1);
  gather256<<<N2C / 4, 256, 0, stream>>>(h1, off1, esrc1, N2C, mean1);
  gemm_cat<<<dim3(79, 2), 256, 0, stream>>>(
      mean1, 256, 256, h1, 256, 256, Wl1, Wr1, 256, b1, h2, 256, N2C, 1);

  // ---- layer 2 + log_softmax ----
  hipMemsetAsync(cnt2, 0, (size_t)2000 * 4, stream);    // cnt2 + cur2
  hist_kernel<<<(E2C + 255) / 256, 256, 0, stream>>>(dst2, E2C, cnt2);
  scan_block<<<1, 256, 0, stream>>>(cnt2, N3C, part2);
  scan_partials<<<1, 1024, 0, stream>>>(part2, 1);
  add_offsets<<<(N3C + 255) / 256, 256, 0, stream>>>(cnt2, part2, N3C, off2);
  fill_kernel<<<(E2C + 255) / 256, 256, 0, stream>>>(src2, dst2, E2C, off2, cur2, esrc2);
  gather256<<<N3C / 4, 256, 0, stream>>>(h2, off2, esrc2, N3C, mean2);
  layer2_lsm<<<N3C, 64, 0, stream>>>(mean2, h2, Wl2, Wr2, b2, out);
}

// Round 3
// 803.713 us; speedup vs baseline: 2.4052x; 1.2098x over previous
//
#include <hip/hip_runtime.h>
#include <cstdint>
#include <cstddef>
#include <cmath>

// Problem constants (fixed by the reference)
#define N0C 600000
#define N1C 100000
#define N2C 10000
#define N3C 1000
#define E0C 1000000
#define E1C 100000
#define E2C 10000

typedef unsigned short u16;
typedef unsigned int u32;
typedef __attribute__((ext_vector_type(8))) short bf16x8;
typedef __attribute__((ext_vector_type(4))) float f32x4;

__device__ __forceinline__ u16 f2b(float x) {
  u32 u = __builtin_bit_cast(u32, x);
  u32 r = (u + 0x7fffu + ((u >> 16) & 1u)) >> 16;  // RNE
  return (u16)r;
}
__device__ __forceinline__ float b2f(u16 h) {
  u32 u = ((u32)h) << 16;
  return __builtin_bit_cast(float, u);
}

// -------------------- CSR build: histogram --------------------
__global__ __launch_bounds__(256) void hist_kernel(
    const int* __restrict__ dst, int E, int* __restrict__ cnt) {
  int i = blockIdx.x * blockDim.x + threadIdx.x;
  if (i < E) atomicAdd(&cnt[dst[i]], 1);
}

// -------------------- CSR build: block-level inclusive scan --------------------
__global__ __launch_bounds__(256) void scan_block(
    int* __restrict__ data, int n, int* __restrict__ partials) {
  __shared__ int sdata[256];
  const int t = threadIdx.x;
  const int base = blockIdx.x * 1024;
  const int idx = base + t * 4;
  int v[4];
  int sum = 0;
#pragma unroll
  for (int k = 0; k < 4; k++) {
    int x = (idx + k < n) ? data[idx + k] : 0;
    v[k] = x; sum += x;
  }
  sdata[t] = sum;
  __syncthreads();
  for (int off = 1; off < 256; off <<= 1) {
    int x = (t >= off) ? sdata[t - off] : 0;
    __syncthreads();
    sdata[t] += x;
    __syncthreads();
  }
  int run = (t > 0) ? sdata[t - 1] : 0;
#pragma unroll
  for (int k = 0; k < 4; k++) {
    run += v[k];
    if (idx + k < n) data[idx + k] = run;  // inclusive, in place
  }
  if (t == 255) partials[blockIdx.x] = sdata[255];
}

__global__ __launch_bounds__(1024) void scan_partials(int* __restrict__ partials, int nb) {
  __shared__ int sdata[1024];
  const int t = threadIdx.x;
  sdata[t] = (t < nb) ? partials[t] : 0;
  __syncthreads();
  for (int off = 1; off < 1024; off <<= 1) {
    int x = (t >= off) ? sdata[t - off] : 0;
    __syncthreads();
    sdata[t] += x;
    __syncthreads();
  }
  int ex = (t > 0) ? sdata[t - 1] : 0;
  if (t < nb) partials[t] = ex;
}

__global__ __launch_bounds__(256) void add_offsets(
    const int* __restrict__ incl, const int* __restrict__ partials, int n,
    int* __restrict__ off) {
  int i = blockIdx.x * blockDim.x + threadIdx.x;
  if (i < n) off[i + 1] = incl[i] + partials[i >> 10];
  if (i == 0) off[0] = 0;
}

__global__ __launch_bounds__(256) void fill_kernel(
    const int* __restrict__ src, const int* __restrict__ dst, int E,
    const int* __restrict__ off, int* __restrict__ cur, int* __restrict__ esrc) {
  int i = blockIdx.x * blockDim.x + threadIdx.x;
  if (i < E) {
    int d = dst[i];
    int p = atomicAdd(&cur[d], 1);
    esrc[off[d] + p] = src[i];
  }
}

// -------------------- conversions --------------------
__global__ __launch_bounds__(256) void cvt_f32_bf16(
    const float* __restrict__ in, u16* __restrict__ out, int n4) {
  int i = blockIdx.x * blockDim.x + threadIdx.x;
  if (i < n4) {
    float4 v = *(const float4*)(in + (size_t)i * 4);
    ushort4 o;
    o.x = f2b(v.x); o.y = f2b(v.y); o.z = f2b(v.z); o.w = f2b(v.w);
    *(ushort4*)(out + (size_t)i * 4) = o;
  }
}

// Wt[n][k] (n in [0,256), k in [0,2*Kh)): transposed concat of Wl;Wr, bf16
__global__ __launch_bounds__(256) void cvt_wt(
    const float* __restrict__ Wl, const float* __restrict__ Wr, int Kh,
    u16* __restrict__ Wt) {
  int Ktot = 2 * Kh;
  int idx = blockIdx.x * blockDim.x + threadIdx.x;
  if (idx >= 256 * Ktot) return;
  int n = idx / Ktot, k = idx - n * Ktot;
  float v = (k < Kh) ? Wl[(size_t)k * 256 + n] : Wr[(size_t)(k - Kh) * 256 + n];
  Wt[idx] = f2b(v);
}

// -------------------- CSR gather-mean (bf16 out) --------------------
// dim=128, f32 input: one wave per node; lane handles 2 floats.
__global__ __launch_bounds__(256) void gather128_bf16(
    const float* __restrict__ X, const int* __restrict__ off,
    const int* __restrict__ esrc, int Nt, u16* __restrict__ mean) {
  int w = (blockIdx.x * blockDim.x + threadIdx.x) >> 6;
  int lane = threadIdx.x & 63;
  if (w >= Nt) return;
  int s = off[w], e = off[w + 1];
  float ax = 0.f, ay = 0.f;
  int j = s;
  for (; j + 1 < e; j += 2) {
    int s0 = esrc[j], s1 = esrc[j + 1];
    float2 v0 = *(const float2*)(X + (size_t)s0 * 128 + lane * 2);
    float2 v1 = *(const float2*)(X + (size_t)s1 * 128 + lane * 2);
    ax += v0.x + v1.x; ay += v0.y + v1.y;
  }
  if (j < e) {
    int s0 = esrc[j];
    float2 v0 = *(const float2*)(X + (size_t)s0 * 128 + lane * 2);
    ax += v0.x; ay += v0.y;
  }
  float inv = 1.0f / fmaxf((float)(e - s), 1.0f);
  u32 p = ((u32)f2b(ay * inv) << 16) | (u32)f2b(ax * inv);
  ((u32*)(mean + (size_t)w * 128))[lane] = p;
}

// dim=256, bf16 input: one wave per node; lane handles 4 elements.
__global__ __launch_bounds__(256) void gather256_bf16(
    const u16* __restrict__ X, const int* __restrict__ off,
    const int* __restrict__ esrc, int Nt, u16* __restrict__ mean) {
  int w = (blockIdx.x * blockDim.x + threadIdx.x) >> 6;
  int lane = threadIdx.x & 63;
  if (w >= Nt) return;
  int s = off[w], e = off[w + 1];
  float a0 = 0.f, a1 = 0.f, a2 = 0.f, a3 = 0.f;
  int j = s;
  for (; j + 1 < e; j += 2) {
    int s0 = esrc[j], s1 = esrc[j + 1];
    ushort4 v0 = *(const ushort4*)(X + (size_t)s0 * 256 + lane * 4);
    ushort4 v1 = *(const ushort4*)(X + (size_t)s1 * 256 + lane * 4);
    a0 += b2f(v0.x) + b2f(v1.x); a1 += b2f(v0.y) + b2f(v1.y);
    a2 += b2f(v0.z) + b2f(v1.z); a3 += b2f(v0.w) + b2f(v1.w);
  }
  if (j < e) {
    int s0 = esrc[j];
    ushort4 v0 = *(const ushort4*)(X + (size_t)s0 * 256 + lane * 4);
    a0 += b2f(v0.x); a1 += b2f(v0.y); a2 += b2f(v0.z); a3 += b2f(v0.w);
  }
  float inv = 1.0f / fmaxf((float)(e - s), 1.0f);
  ushort4 o;
  o.x = f2b(a0 * inv); o.y = f2b(a1 * inv); o.z = f2b(a2 * inv); o.w = f2b(a3 * inv);
  *(ushort4*)(mean + (size_t)w * 256 + lane * 4) = o;
}

// -------------------- bf16 MFMA GEMM (LDS-free, concat-K) --------------------
// C[M,256] = relu?( [A1 | A2] @ Wt^T + bias ), A1/A2: [M,Kh] bf16 row-major,
// Wt: [256][2*Kh] bf16 (pre-transposed concat of B1;B2). Block = 128x128 tile,
// 4 waves in 2x2; wave = 64x64 via 4x4 grid of 16x16x32 MFMAs; frags read
// directly from global (A rows contiguous; Wt is L2-resident).
__global__ __launch_bounds__(256) void gemm_mfma(
    const u16* __restrict__ A1, const u16* __restrict__ A2, int Kh,
    const u16* __restrict__ Wt, const float* __restrict__ bias,
    u16* __restrict__ C, int M, int do_relu) {
  const int tid = threadIdx.x;
  const int wave = tid >> 6, lane = tid & 63;
  const int lr = lane & 15, quad = lane >> 4;
  const int wr = wave >> 1, wc = wave & 1;
  const int rowBase = blockIdx.x * 128 + wr * 64;
  const int colBase = blockIdx.y * 128 + wc * 64;
  const int Ktot = 2 * Kh;

  f32x4 acc[4][4] = {};

  size_t aoff[4];
#pragma unroll
  for (int mt = 0; mt < 4; mt++) {
    int r = rowBase + mt * 16 + lr;
    if (r >= M) r = M - 1;
    aoff[mt] = (size_t)r * Kh;
  }
  const u16* wrow[4];
  float bs[4];
#pragma unroll
  for (int nt = 0; nt < 4; nt++) {
    int n = colBase + nt * 16 + lr;
    wrow[nt] = Wt + (size_t)n * Ktot;
    bs[nt] = bias[n];
  }

#pragma unroll
  for (int half = 0; half < 2; half++) {
    const u16* Asrc = half ? A2 : A1;
    const int kb = half * Kh;
    for (int kt = 0; kt < Kh; kt += 32) {
      bf16x8 af[4], bfr[4];
#pragma unroll
      for (int mt = 0; mt < 4; mt++)
        af[mt] = *(const bf16x8*)(Asrc + aoff[mt] + kt + quad * 8);
#pragma unroll
      for (int nt = 0; nt < 4; nt++)
        bfr[nt] = *(const bf16x8*)(wrow[nt] + kb + kt + quad * 8);
#pragma unroll
      for (int mt = 0; mt < 4; mt++)
#pragma unroll
        for (int nt = 0; nt < 4; nt++)
          acc[mt][nt] = __builtin_amdgcn_mfma_f32_16x16x32_bf16(
              af[mt], bfr[nt], acc[mt][nt], 0, 0, 0);
    }
  }

  // epilogue: C/D layout col=lane&15, row=quad*4+reg
#pragma unroll
  for (int mt = 0; mt < 4; mt++) {
#pragma unroll
    for (int reg = 0; reg < 4; reg++) {
      int row = rowBase + mt * 16 + quad * 4 + reg;
      if (row < M) {
#pragma unroll
        for (int nt = 0; nt < 4; nt++) {
          float v = acc[mt][nt][reg] + bs[nt];
          if (do_relu) v = fmaxf(v, 0.f);
          C[(size_t)row * 256 + colBase + nt * 16 + lr] = f2b(v);
        }
      }
    }
  }
}

// -------------------- layer 2 + log_softmax (bf16 inputs) --------------------
__global__ __launch_bounds__(64) void layer2_lsm(
    const u16* __restrict__ mean2, const u16* __restrict__ h2,
    const float* __restrict__ Wl2, const float* __restrict__ Wr2,
    const float* __restrict__ b2, float* __restrict__ out) {
  __shared__ float arow[512];
  const int i = blockIdx.x;
  const int lane = threadIdx.x;
  for (int t = lane; t < 256; t += 64) {
    arow[t] = b2f(mean2[(size_t)i * 256 + t]);
    arow[256 + t] = b2f(h2[(size_t)i * 256 + t]);
  }
  __syncthreads();
  float acc = 0.0f;
  if (lane < 47) {
    acc = b2[lane];
#pragma unroll 4
    for (int k = 0; k < 256; k++) acc += arow[k] * Wl2[k * 47 + lane];
#pragma unroll 4
    for (int k = 0; k < 256; k++) acc += arow[256 + k] * Wr2[k * 47 + lane];
  }
  float v = (lane < 47) ? acc : -INFINITY;
#pragma unroll
  for (int off = 32; off >= 1; off >>= 1) v = fmaxf(v, __shfl_xor(v, off, 64));
  float e = (lane < 47) ? expf(acc - v) : 0.0f;
  float s = e;
#pragma unroll
  for (int off = 32; off >= 1; off >>= 1) s += __shfl_xor(s, off, 64);
  if (lane < 47) out[(size_t)i * 47 + lane] = acc - v - logf(s);
}

// -------------------- launch --------------------
extern "C" void kernel_launch(void* const* d_in, const int* in_sizes, int n_in,
                              void* d_out, int out_size, void* d_ws, size_t ws_size,
                              hipStream_t stream) {
  (void)in_sizes; (void)n_in; (void)out_size; (void)ws_size;
  const float* x   = (const float*)d_in[0];
  const int* src0  = (const int*)d_in[1];
  const int* dst0  = (const int*)d_in[2];
  const int* src1  = (const int*)d_in[3];
  const int* dst1  = (const int*)d_in[4];
  const int* src2  = (const int*)d_in[5];
  const int* dst2  = (const int*)d_in[6];
  const float* Wl0 = (const float*)d_in[7];
  const float* Wr0 = (const float*)d_in[8];
  const float* b0  = (const float*)d_in[9];
  const float* Wl1 = (const float*)d_in[10];
  const float* Wr1 = (const float*)d_in[11];
  const float* b1  = (const float*)d_in[12];
  const float* Wl2 = (const float*)d_in[13];
  const float* Wr2 = (const float*)d_in[14];
  const float* b2  = (const float*)d_in[15];

  // ---- workspace layout (~119 MB; all blocks 256B-aligned) ----
  char* p = (char*)d_ws;
  u16* mean0 = (u16*)p; p += (size_t)N1C * 128 * 2;   // 25.6 MB
  u16* xb    = (u16*)p; p += (size_t)N1C * 128 * 2;   // 25.6 MB (x[:N1] bf16)
  u16* h1    = (u16*)p; p += (size_t)N1C * 256 * 2;   // 51.2 MB
  u16* mean1 = (u16*)p; p += (size_t)N2C * 256 * 2;   // 5.12 MB
  u16* h2    = (u16*)p; p += (size_t)N2C * 256 * 2;   // 5.12 MB
  u16* mean2 = (u16*)p; p += (size_t)N3C * 256 * 2;   // 0.512 MB
  u16* Wt0   = (u16*)p; p += (size_t)256 * 256 * 2;   // 128 KB
  u16* Wt1   = (u16*)p; p += (size_t)256 * 512 * 2;   // 256 KB
  int* cnt0  = (int*)p;
  int* cur0  = cnt0 + 100000;
  int* off0  = cur0 + 100000;
  int* part0 = off0 + 100256;   // padded past 100001
  int* esrc0 = part0 + 256;
  int* cnt1  = esrc0 + 1000000;
  int* cur1  = cnt1 + 10000;
  int* off1  = cur1 + 10000;
  int* part1 = off1 + 10256;
  int* esrc1 = part1 + 256;
  int* cnt2  = esrc1 + 100000;
  int* cur2  = cnt2 + 1000;
  int* off2  = cur2 + 1000;
  int* part2 = off2 + 1256;
  int* esrc2 = part2 + 256;
  float* out = (float*)d_out;

  // ---- conversions (independent of CSR) ----
  cvt_f32_bf16<<<(N1C * 128 / 4 + 255) / 256, 256, 0, stream>>>(x, xb, N1C * 128 / 4);
  cvt_wt<<<(256 * 256 + 255) / 256, 256, 0, stream>>>(Wl0, Wr0, 128, Wt0);
  cvt_wt<<<(256 * 512 + 255) / 256, 256, 0, stream>>>(Wl1, Wr1, 256, Wt1);

  // ---- layer 0 ----
  hipMemsetAsync(cnt0, 0, (size_t)200000 * 4, stream);
  hist_kernel<<<(E0C + 255) / 256, 256, 0, stream>>>(dst0, E0C, cnt0);
  scan_block<<<(N1C + 1023) / 1024, 256, 0, stream>>>(cnt0, N1C, part0);
  scan_partials<<<1, 1024, 0, stream>>>(part0, (N1C + 1023) / 1024);
  add_offsets<<<(N1C + 255) / 256, 256, 0, stream>>>(cnt0, part0, N1C, off0);
  fill_kernel<<<(E0C + 255) / 256, 256, 0, stream>>>(src0, dst0, E0C, off0, cur0, esrc0);
  gather128_bf16<<<N1C / 4, 256, 0, stream>>>(x, off0, esrc0, N1C, mean0);
  gemm_mfma<<<dim3(782, 2), 256, 0, stream>>>(mean0, xb, 128, Wt0, b0, h1, N1C, 1);

  // ---- layer 1 ----
  hipMemsetAsync(cnt1, 0, (size_t)20000 * 4, stream);
  hist_kernel<<<(E1C + 255) / 256, 256, 0, stream>>>(dst1, E1C, cnt1);
  scan_block<<<(N2C + 1023) / 1024, 256, 0, stream>>>(cnt1, N2C, part1);
  scan_partials<<<1, 1024, 0, stream>>>(part1, (N2C + 1023) / 1024);
  add_offsets<<<(N2C + 255) / 256, 256, 0, stream>>>(cnt1, part1, N2C, off1);
  fill_kernel<<<(E1C + 255) / 256, 256, 0, stream>>>(src1, dst1, E1C, off1, cur1, esrc1);
  gather256_bf16<<<N2C / 4, 256, 0, stream>>>(h1, off1, esrc1, N2C, mean1);
  gemm_mfma<<<dim3(79, 2), 256, 0, stream>>>(mean1, h1, 256, Wt1, b1, h2, N2C, 1);

  // ---- layer 2 + log_softmax ----
  hipMemsetAsync(cnt2, 0, (size_t)2000 * 4, stream);
  hist_kernel<<<(E2C + 255) / 256, 256, 0, stream>>>(dst2, E2C, cnt2);
  scan_block<<<1, 256, 0, stream>>>(cnt2, N3C, part2);
  scan_partials<<<1, 1024, 0, stream>>>(part2, 1);
  add_offsets<<<(N3C + 255) / 256, 256, 0, stream>>>(cnt2, part2, N3C, off2);
  fill_kernel<<<(E2C + 255) / 256, 256, 0, stream>>>(src2, dst2, E2C, off2, cur2, esrc2);
  gather256_bf16<<<N3C / 4, 256, 0, stream>>>(h2, off2, esrc2, N3C, mean2);
  layer2_lsm<<<N3C, 64, 0, stream>>>(mean2, h2, Wl2, Wr2, b2, out);
}

// Round 4
// 784.484 us; speedup vs baseline: 2.4641x; 1.0245x over previous
//
#include <hip/hip_runtime.h>
#include <cstdint>
#include <cstddef>
#include <cmath>

// Problem constants (fixed by the reference)
#define N0C 600000
#define N1C 100000
#define N2C 10000
#define N3C 1000
#define E0C 1000000
#define E1C 100000
#define E2C 10000

typedef unsigned short u16;
typedef unsigned int u32;
typedef __attribute__((ext_vector_type(8))) short bf16x8;
typedef __attribute__((ext_vector_type(4))) float f32x4;

__device__ __forceinline__ u16 f2b(float x) {
  u32 u = __builtin_bit_cast(u32, x);
  u32 r = (u + 0x7fffu + ((u >> 16) & 1u)) >> 16;  // RNE
  return (u16)r;
}
__device__ __forceinline__ float b2f(u16 h) {
  u32 u = ((u32)h) << 16;
  return __builtin_bit_cast(float, u);
}

// -------------------- fused CSR build (all 3 layers) --------------------
__global__ __launch_bounds__(256) void hist3(
    const int* __restrict__ d0, const int* __restrict__ d1,
    const int* __restrict__ d2, int* __restrict__ c0, int* __restrict__ c1,
    int* __restrict__ c2) {
  int i = blockIdx.x * blockDim.x + threadIdx.x;
  if (i < E0C) atomicAdd(&c0[d0[i]], 1);
  else if (i < E0C + E1C) atomicAdd(&c1[d1[i - E0C]], 1);
  else if (i < E0C + E1C + E2C) atomicAdd(&c2[d2[i - E0C - E1C]], 1);
}

// blocks [0,98) -> seg0, [98,108) -> seg1, [108,109) -> seg2
__global__ __launch_bounds__(256) void scan_block3(
    int* __restrict__ c0, int* __restrict__ c1, int* __restrict__ c2,
    int* __restrict__ p0, int* __restrict__ p1, int* __restrict__ p2) {
  __shared__ int sdata[256];
  const int b = blockIdx.x;
  int* data; int n; int* partials; int lb;
  if (b < 98)       { data = c0; n = N1C; partials = p0; lb = b; }
  else if (b < 108) { data = c1; n = N2C; partials = p1; lb = b - 98; }
  else              { data = c2; n = N3C; partials = p2; lb = b - 108; }
  const int t = threadIdx.x;
  const int idx = lb * 1024 + t * 4;
  int v[4];
  int sum = 0;
#pragma unroll
  for (int k = 0; k < 4; k++) {
    int x = (idx + k < n) ? data[idx + k] : 0;
    v[k] = x; sum += x;
  }
  sdata[t] = sum;
  __syncthreads();
  for (int off = 1; off < 256; off <<= 1) {
    int x = (t >= off) ? sdata[t - off] : 0;
    __syncthreads();
    sdata[t] += x;
    __syncthreads();
  }
  int run = (t > 0) ? sdata[t - 1] : 0;
#pragma unroll
  for (int k = 0; k < 4; k++) {
    run += v[k];
    if (idx + k < n) data[idx + k] = run;  // inclusive, in place
  }
  if (t == 255) partials[lb] = sdata[255];
}

// block s scans partials of segment s (sizes 98,10,1), 128 threads
__global__ __launch_bounds__(128) void scan_partials3(
    int* __restrict__ p0, int* __restrict__ p1, int* __restrict__ p2) {
  __shared__ int sdata[128];
  int* p; int nb;
  if (blockIdx.x == 0)      { p = p0; nb = 98; }
  else if (blockIdx.x == 1) { p = p1; nb = 10; }
  else                      { p = p2; nb = 1; }
  const int t = threadIdx.x;
  sdata[t] = (t < nb) ? p[t] : 0;
  __syncthreads();
  for (int off = 1; off < 128; off <<= 1) {
    int x = (t >= off) ? sdata[t - off] : 0;
    __syncthreads();
    sdata[t] += x;
    __syncthreads();
  }
  int ex = (t > 0) ? sdata[t - 1] : 0;
  if (t < nb) p[t] = ex;
}

__global__ __launch_bounds__(256) void addoff3(
    const int* __restrict__ c0, const int* __restrict__ c1,
    const int* __restrict__ c2, const int* __restrict__ p0,
    const int* __restrict__ p1, const int* __restrict__ p2,
    int* __restrict__ o0, int* __restrict__ o1, int* __restrict__ o2) {
  int i = blockIdx.x * blockDim.x + threadIdx.x;
  if (i < N1C) {
    o0[i + 1] = c0[i] + p0[i >> 10];
    if (i == 0) o0[0] = 0;
  } else if (i < N1C + N2C) {
    int j = i - N1C;
    o1[j + 1] = c1[j] + p1[j >> 10];
    if (j == 0) o1[0] = 0;
  } else if (i < N1C + N2C + N3C) {
    int j = i - N1C - N2C;
    o2[j + 1] = c2[j] + p2[j >> 10];
    if (j == 0) o2[0] = 0;
  }
}

__global__ __launch_bounds__(256) void fill3(
    const int* __restrict__ s0, const int* __restrict__ d0,
    const int* __restrict__ s1, const int* __restrict__ d1,
    const int* __restrict__ s2, const int* __restrict__ d2,
    const int* __restrict__ o0, const int* __restrict__ o1,
    const int* __restrict__ o2, int* __restrict__ u0, int* __restrict__ u1,
    int* __restrict__ u2, int* __restrict__ e0, int* __restrict__ e1,
    int* __restrict__ e2) {
  int i = blockIdx.x * blockDim.x + threadIdx.x;
  if (i < E0C) {
    int d = d0[i]; int p = atomicAdd(&u0[d], 1); e0[o0[d] + p] = s0[i];
  } else if (i < E0C + E1C) {
    int j = i - E0C;
    int d = d1[j]; int p = atomicAdd(&u1[d], 1); e1[o1[d] + p] = s1[j];
  } else if (i < E0C + E1C + E2C) {
    int j = i - E0C - E1C;
    int d = d2[j]; int p = atomicAdd(&u2[d], 1); e2[o2[d] + p] = s2[j];
  }
}

// -------------------- conversions --------------------
__global__ __launch_bounds__(256) void cvt_f32_bf16(
    const float* __restrict__ in, u16* __restrict__ out, int n4) {
  int i = blockIdx.x * blockDim.x + threadIdx.x;
  if (i < n4) {
    float4 v = *(const float4*)(in + (size_t)i * 4);
    ushort4 o;
    o.x = f2b(v.x); o.y = f2b(v.y); o.z = f2b(v.z); o.w = f2b(v.w);
    *(ushort4*)(out + (size_t)i * 4) = o;
  }
}

// both weight transposes in one kernel:
// Wt0[n][k] n<256,k<256 from (Wl0,Wr0,Kh=128); Wt1[n][k] n<256,k<512
__global__ __launch_bounds__(256) void cvt_wt2(
    const float* __restrict__ Wl0, const float* __restrict__ Wr0,
    const float* __restrict__ Wl1, const float* __restrict__ Wr1,
    u16* __restrict__ Wt0, u16* __restrict__ Wt1) {
  int idx = blockIdx.x * blockDim.x + threadIdx.x;
  if (idx < 256 * 256) {
    int n = idx >> 8, k = idx & 255;
    float v = (k < 128) ? Wl0[(size_t)k * 256 + n] : Wr0[(size_t)(k - 128) * 256 + n];
    Wt0[idx] = f2b(v);
  } else if (idx < 256 * 256 + 256 * 512) {
    int j = idx - 256 * 256;
    int n = j >> 9, k = j & 511;
    float v = (k < 256) ? Wl1[(size_t)k * 256 + n] : Wr1[(size_t)(k - 256) * 256 + n];
    Wt1[j] = f2b(v);
  }
}

// -------------------- CSR gather-mean (bf16 table, bf16 out) --------------------
// dim=128 bf16: row = 256B = 64 lanes x u32 (2 elems/lane). 4x unroll.
__global__ __launch_bounds__(256) void gather128_bf16(
    const u16* __restrict__ X, const int* __restrict__ off,
    const int* __restrict__ esrc, int Nt, u16* __restrict__ mean) {
  int w = (blockIdx.x * blockDim.x + threadIdx.x) >> 6;
  int lane = threadIdx.x & 63;
  if (w >= Nt) return;
  int s = off[w], e = off[w + 1];
  const u32* Xr = (const u32*)X;
  float a0 = 0.f, a1 = 0.f;
  int j = s;
  for (; j + 3 < e; j += 4) {
    u32 r0 = Xr[(size_t)esrc[j + 0] * 64 + lane];
    u32 r1 = Xr[(size_t)esrc[j + 1] * 64 + lane];
    u32 r2 = Xr[(size_t)esrc[j + 2] * 64 + lane];
    u32 r3 = Xr[(size_t)esrc[j + 3] * 64 + lane];
    a0 += b2f((u16)r0) + b2f((u16)r1) + b2f((u16)r2) + b2f((u16)r3);
    a1 += b2f((u16)(r0 >> 16)) + b2f((u16)(r1 >> 16)) +
          b2f((u16)(r2 >> 16)) + b2f((u16)(r3 >> 16));
  }
  for (; j < e; j++) {
    u32 r = Xr[(size_t)esrc[j] * 64 + lane];
    a0 += b2f((u16)r);
    a1 += b2f((u16)(r >> 16));
  }
  float inv = 1.0f / fmaxf((float)(e - s), 1.0f);
  u32 p = ((u32)f2b(a1 * inv) << 16) | (u32)f2b(a0 * inv);
  ((u32*)(mean + (size_t)w * 128))[lane] = p;
}

// dim=256 bf16: row = 512B = 64 lanes x ushort4. 4x unroll.
__global__ __launch_bounds__(256) void gather256_bf16(
    const u16* __restrict__ X, const int* __restrict__ off,
    const int* __restrict__ esrc, int Nt, u16* __restrict__ mean) {
  int w = (blockIdx.x * blockDim.x + threadIdx.x) >> 6;
  int lane = threadIdx.x & 63;
  if (w >= Nt) return;
  int s = off[w], e = off[w + 1];
  float a0 = 0.f, a1 = 0.f, a2 = 0.f, a3 = 0.f;
  int j = s;
  for (; j + 3 < e; j += 4) {
    ushort4 v0 = *(const ushort4*)(X + (size_t)esrc[j + 0] * 256 + lane * 4);
    ushort4 v1 = *(const ushort4*)(X + (size_t)esrc[j + 1] * 256 + lane * 4);
    ushort4 v2 = *(const ushort4*)(X + (size_t)esrc[j + 2] * 256 + lane * 4);
    ushort4 v3 = *(const ushort4*)(X + (size_t)esrc[j + 3] * 256 + lane * 4);
    a0 += b2f(v0.x) + b2f(v1.x) + b2f(v2.x) + b2f(v3.x);
    a1 += b2f(v0.y) + b2f(v1.y) + b2f(v2.y) + b2f(v3.y);
    a2 += b2f(v0.z) + b2f(v1.z) + b2f(v2.z) + b2f(v3.z);
    a3 += b2f(v0.w) + b2f(v1.w) + b2f(v2.w) + b2f(v3.w);
  }
  for (; j < e; j++) {
    ushort4 v0 = *(const ushort4*)(X + (size_t)esrc[j] * 256 + lane * 4);
    a0 += b2f(v0.x); a1 += b2f(v0.y); a2 += b2f(v0.z); a3 += b2f(v0.w);
  }
  float inv = 1.0f / fmaxf((float)(e - s), 1.0f);
  ushort4 o;
  o.x = f2b(a0 * inv); o.y = f2b(a1 * inv); o.z = f2b(a2 * inv); o.w = f2b(a3 * inv);
  *(ushort4*)(mean + (size_t)w * 256 + lane * 4) = o;
}

// -------------------- bf16 MFMA GEMM (LDS-free, concat-K) --------------------
__global__ __launch_bounds__(256) void gemm_mfma(
    const u16* __restrict__ A1, const u16* __restrict__ A2, int Kh,
    const u16* __restrict__ Wt, const float* __restrict__ bias,
    u16* __restrict__ C, int M, int do_relu) {
  const int tid = threadIdx.x;
  const int wave = tid >> 6, lane = tid & 63;
  const int lr = lane & 15, quad = lane >> 4;
  const int wr = wave >> 1, wc = wave & 1;
  const int rowBase = blockIdx.x * 128 + wr * 64;
  const int colBase = blockIdx.y * 128 + wc * 64;
  const int Ktot = 2 * Kh;

  f32x4 acc[4][4] = {};

  size_t aoff[4];
#pragma unroll
  for (int mt = 0; mt < 4; mt++) {
    int r = rowBase + mt * 16 + lr;
    if (r >= M) r = M - 1;
    aoff[mt] = (size_t)r * Kh;
  }
  const u16* wrow[4];
  float bs[4];
#pragma unroll
  for (int nt = 0; nt < 4; nt++) {
    int n = colBase + nt * 16 + lr;
    wrow[nt] = Wt + (size_t)n * Ktot;
    bs[nt] = bias[n];
  }

#pragma unroll
  for (int half = 0; half < 2; half++) {
    const u16* Asrc = half ? A2 : A1;
    const int kb = half * Kh;
    for (int kt = 0; kt < Kh; kt += 32) {
      bf16x8 af[4], bfr[4];
#pragma unroll
      for (int mt = 0; mt < 4; mt++)
        af[mt] = *(const bf16x8*)(Asrc + aoff[mt] + kt + quad * 8);
#pragma unroll
      for (int nt = 0; nt < 4; nt++)
        bfr[nt] = *(const bf16x8*)(wrow[nt] + kb + kt + quad * 8);
#pragma unroll
      for (int mt = 0; mt < 4; mt++)
#pragma unroll
        for (int nt = 0; nt < 4; nt++)
          acc[mt][nt] = __builtin_amdgcn_mfma_f32_16x16x32_bf16(
              af[mt], bfr[nt], acc[mt][nt], 0, 0, 0);
    }
  }

  // C/D layout: col=lane&15, row=quad*4+reg
#pragma unroll
  for (int mt = 0; mt < 4; mt++) {
#pragma unroll
    for (int reg = 0; reg < 4; reg++) {
      int row = rowBase + mt * 16 + quad * 4 + reg;
      if (row < M) {
#pragma unroll
        for (int nt = 0; nt < 4; nt++) {
          float v = acc[mt][nt][reg] + bs[nt];
          if (do_relu) v = fmaxf(v, 0.f);
          C[(size_t)row * 256 + colBase + nt * 16 + lr] = f2b(v);
        }
      }
    }
  }
}

// -------------------- layer 2 + log_softmax (bf16 inputs) --------------------
__global__ __launch_bounds__(64) void layer2_lsm(
    const u16* __restrict__ mean2, const u16* __restrict__ h2,
    const float* __restrict__ Wl2, const float* __restrict__ Wr2,
    const float* __restrict__ b2, float* __restrict__ out) {
  __shared__ float arow[512];
  const int i = blockIdx.x;
  const int lane = threadIdx.x;
  for (int t = lane; t < 256; t += 64) {
    arow[t] = b2f(mean2[(size_t)i * 256 + t]);
    arow[256 + t] = b2f(h2[(size_t)i * 256 + t]);
  }
  __syncthreads();
  float acc = 0.0f;
  if (lane < 47) {
    acc = b2[lane];
#pragma unroll 4
    for (int k = 0; k < 256; k++) acc += arow[k] * Wl2[k * 47 + lane];
#pragma unroll 4
    for (int k = 0; k < 256; k++) acc += arow[256 + k] * Wr2[k * 47 + lane];
  }
  float v = (lane < 47) ? acc : -INFINITY;
#pragma unroll
  for (int off = 32; off >= 1; off >>= 1) v = fmaxf(v, __shfl_xor(v, off, 64));
  float e = (lane < 47) ? expf(acc - v) : 0.0f;
  float s = e;
#pragma unroll
  for (int off = 32; off >= 1; off >>= 1) s += __shfl_xor(s, off, 64);
  if (lane < 47) out[(size_t)i * 47 + lane] = acc - v - logf(s);
}

// -------------------- launch --------------------
extern "C" void kernel_launch(void* const* d_in, const int* in_sizes, int n_in,
                              void* d_out, int out_size, void* d_ws, size_t ws_size,
                              hipStream_t stream) {
  (void)in_sizes; (void)n_in; (void)out_size; (void)ws_size;
  const float* x   = (const float*)d_in[0];
  const int* src0  = (const int*)d_in[1];
  const int* dst0  = (const int*)d_in[2];
  const int* src1  = (const int*)d_in[3];
  const int* dst1  = (const int*)d_in[4];
  const int* src2  = (const int*)d_in[5];
  const int* dst2  = (const int*)d_in[6];
  const float* Wl0 = (const float*)d_in[7];
  const float* Wr0 = (const float*)d_in[8];
  const float* b0  = (const float*)d_in[9];
  const float* Wl1 = (const float*)d_in[10];
  const float* Wr1 = (const float*)d_in[11];
  const float* b1  = (const float*)d_in[12];
  const float* Wl2 = (const float*)d_in[13];
  const float* Wr2 = (const float*)d_in[14];
  const float* b2  = (const float*)d_in[15];

  // ---- workspace layout (~246 MB of the ~1.2 GB ws; 256B-aligned blocks) ----
  char* p = (char*)d_ws;
  u16* xb    = (u16*)p; p += (size_t)N0C * 128 * 2;   // 153.6 MB (full x, bf16)
  u16* mean0 = (u16*)p; p += (size_t)N1C * 128 * 2;   // 25.6 MB
  u16* h1    = (u16*)p; p += (size_t)N1C * 256 * 2;   // 51.2 MB
  u16* mean1 = (u16*)p; p += (size_t)N2C * 256 * 2;   // 5.12 MB
  u16* h2    = (u16*)p; p += (size_t)N2C * 256 * 2;   // 5.12 MB
  u16* mean2 = (u16*)p; p += (size_t)N3C * 256 * 2;   // 0.512 MB
  u16* Wt0   = (u16*)p; p += (size_t)256 * 256 * 2;   // 128 KB
  u16* Wt1   = (u16*)p; p += (size_t)256 * 512 * 2;   // 256 KB
  // contiguous cnt/cur block -> single memset (222,000 ints)
  int* cnt0  = (int*)p;
  int* cur0  = cnt0 + 100000;
  int* cnt1  = cur0 + 100000;
  int* cur1  = cnt1 + 10000;
  int* cnt2  = cur1 + 10000;
  int* cur2  = cnt2 + 1000;
  int* off0  = cur2 + 1000 + 48;   // pad to 256B boundary
  int* off1  = off0 + 100096;
  int* off2  = off1 + 10112;
  int* part0 = off2 + 1088;
  int* part1 = part0 + 128;
  int* part2 = part1 + 128;
  int* esrc0 = part2 + 128;
  int* esrc1 = esrc0 + 1000000;
  int* esrc2 = esrc1 + 100000;
  float* out = (float*)d_out;

  // ---- fused CSR build (all layers) ----
  hipMemsetAsync(cnt0, 0, (size_t)222000 * 4, stream);
  hist3<<<(E0C + E1C + E2C + 255) / 256, 256, 0, stream>>>(
      dst0, dst1, dst2, cnt0, cnt1, cnt2);
  scan_block3<<<109, 256, 0, stream>>>(cnt0, cnt1, cnt2, part0, part1, part2);
  scan_partials3<<<3, 128, 0, stream>>>(part0, part1, part2);
  addoff3<<<(N1C + N2C + N3C + 255) / 256, 256, 0, stream>>>(
      cnt0, cnt1, cnt2, part0, part1, part2, off0, off1, off2);
  fill3<<<(E0C + E1C + E2C + 255) / 256, 256, 0, stream>>>(
      src0, dst0, src1, dst1, src2, dst2, off0, off1, off2,
      cur0, cur1, cur2, esrc0, esrc1, esrc2);

  // ---- conversions (x right before gather for L3 residency) ----
  cvt_wt2<<<(256 * 256 + 256 * 512 + 255) / 256, 256, 0, stream>>>(
      Wl0, Wr0, Wl1, Wr1, Wt0, Wt1);
  cvt_f32_bf16<<<(N0C * 128 / 4 + 255) / 256, 256, 0, stream>>>(
      x, xb, N0C * 128 / 4);

  // ---- layer 0 ----
  gather128_bf16<<<N1C / 4, 256, 0, stream>>>(xb, off0, esrc0, N1C, mean0);
  gemm_mfma<<<dim3(782, 2), 256, 0, stream>>>(mean0, xb, 128, Wt0, b0, h1, N1C, 1);

  // ---- layer 1 ----
  gather256_bf16<<<N2C / 4, 256, 0, stream>>>(h1, off1, esrc1, N2C, mean1);
  gemm_mfma<<<dim3(79, 2), 256, 0, stream>>>(mean1, h1, 256, Wt1, b1, h2, N2C, 1);

  // ---- layer 2 + log_softmax ----
  gather256_bf16<<<N3C / 4, 256, 0, stream>>>(h2, off2, esrc2, N3C, mean2);
  layer2_lsm<<<N3C, 64, 0, stream>>>(mean2, h2, Wl2, Wr2, b2, out);
}